// Round 3
// baseline (2392.579 us; speedup 1.0000x reference)
//
#include <hip/hip_runtime.h>
#include <hip/hip_bf16.h>

// ---------------------------------------------------------------------------
// LSTM-CRF forward on MI355X.
// R11 = R10 autonomous-wave LSTM + canary/cached-read exchange:
//   R10 post-mortem: 314 MB FETCH/dispatch = 128 waves x 16 KB sc0sc1 spin
//   refetch per step saturating the uncached read path (~550 GB/s). Fix:
//   - producers publish h (sc0sc1, write-through) -> vmcnt(0) -> ONE canary
//     dword (sc0sc1) per wave per step (R5/R8-validated release pattern).
//   - consumers spin on 64 canary dwords (256 B/attempt, not 16 KB), then
//     read the 16 KB fragment data with PLAIN CACHED loads -> per-XCD L2
//     dedup cuts IF traffic ~16x. Data lines enter L2 only post-ready.
//   - MFMA once per step (no retry-MFMA); sentinel machinery deleted.
// Everything else (wave structure, gate-interleaved B, quad transpose,
// GEMMs, CRF, prep) R10-verbatim.
// ---------------------------------------------------------------------------

#define Bv 32
#define Tv 256
#define Ev 300
#define HDv 256
#define Kv 64
#define MROWS (Bv * Tv)          // 8192
#define K0PAD 320                // 301 padded to mult of 32
#define GATES 1024               // 4*HD
#define WFRAG_Z 262144           // shorts per (layer,dir) weight block

typedef __bf16 v8bf __attribute__((ext_vector_type(8)));
typedef float  v4f  __attribute__((ext_vector_type(4)));
typedef unsigned int v4u __attribute__((ext_vector_type(4)));

union AB { v4u u; v8bf v; };

__device__ __forceinline__ unsigned short f2bf(float f) {
    unsigned u = __float_as_uint(f);
    unsigned r = (u + 0x7fffu + ((u >> 16) & 1u)) >> 16;
    return (unsigned short)r;
}
__device__ __forceinline__ float sigf(float x) { return 1.0f / (1.0f + __expf(-x)); }
__device__ __forceinline__ float tanhf2(float x) {
    x = fminf(15.f, fmaxf(-15.f, x));
    float e = __expf(2.f * x);
    return (e - 1.f) / (e + 1.f);
}
// IF-coherent primitives (bypass L1/L2).
__device__ __forceinline__ unsigned int ld_sys32(const unsigned int* p) {
    unsigned int r;
    asm volatile("global_load_dword %0, %1, off sc0 sc1"
                 : "=v"(r) : "v"(p) : "memory");
    return r;
}
__device__ __forceinline__ void st_sys16(void* p, unsigned short v) {
    unsigned int vv = v;
    asm volatile("global_store_short %0, %1, off sc0 sc1"
                 :: "v"(p), "v"(vv) : "memory");
}
__device__ __forceinline__ void st_sys32(unsigned int* p, unsigned int v) {
    asm volatile("global_store_dword %0, %1, off sc0 sc1"
                 :: "v"(p), "v"(v) : "memory");
}

// ---------------- prep kernels ----------------

__global__ void conv_weights(const float* w0f, const float* w0b,
                             const float* w1f, const float* w1b,
                             const float* outw,
                             unsigned short* dW0, unsigned short* dW1,
                             unsigned short* dOW) {
    int z = blockIdx.z;
    const float* src; unsigned short* dst; int rows, kin, kout;
    if (z == 0)      { src = w0f;  dst = dW0;                rows = 1024; kin = 301; kout = K0PAD; }
    else if (z == 1) { src = w0b;  dst = dW0 + 1024 * K0PAD; rows = 1024; kin = 301; kout = K0PAD; }
    else if (z == 2) { src = w1f;  dst = dW1;                rows = 1024; kin = 512; kout = 512; }
    else if (z == 3) { src = w1b;  dst = dW1 + 1024 * 512;   rows = 1024; kin = 512; kout = 512; }
    else             { src = outw; dst = dOW;                rows = 64;   kin = 512; kout = 512; }
    int idx = blockIdx.x * 256 + threadIdx.x;
    if (idx >= rows * kout) return;
    int j = idx / kout, k = idx - j * kout;
    dst[idx] = (k < kin) ? f2bf(src[j * kin + k]) : (unsigned short)0;
}

// Whh [1024,256] fp32 -> bf16 MFMA B-fragment order, gate-interleaved:
// per (layer*2+dir) z: [wb(64)][kt(8)][lane(64)][e(8)]
// B-row n = lane&15 = 4*jsub + gate; value = Whh[gate*256 + wb*4 + jsub][k],
// k = kt*32 + (lane>>4)*8 + e.
__global__ void whh_frag(const float* h0f, const float* h0b,
                         const float* h1f, const float* h1b, unsigned short* Wfrag) {
    int z = blockIdx.z;
    const float* src = (z == 0) ? h0f : (z == 1) ? h0b : (z == 2) ? h1f : h1b;
    unsigned short* dst = Wfrag + (size_t)z * WFRAG_Z;
    int idx = blockIdx.x * 256 + threadIdx.x;          // 0..262143
    int e = idx & 7, ln = (idx >> 3) & 63, kt = (idx >> 9) & 7, wb = idx >> 12;
    int n = ln & 15;
    int jsub = n >> 2, gate = n & 3;
    int row = gate * 256 + wb * 4 + jsub;
    int k = kt * 32 + (ln >> 4) * 8 + e;
    dst[idx] = f2bf(src[row * 256 + k]);
}

__global__ void bias_sum(const float* a0, const float* b0, const float* a1, const float* b1,
                         const float* a2, const float* b2, const float* a3, const float* b3,
                         float* bias) {
    int idx = blockIdx.x * 256 + threadIdx.x;      // 0..4095
    int dl = idx >> 10, j = idx & 1023;
    const float* A = (dl == 0) ? a0 : (dl == 1) ? a1 : (dl == 2) ? a2 : a3;
    const float* B = (dl == 0) ? b0 : (dl == 1) ? b1 : (dl == 2) ? b2 : b3;
    bias[idx] = A[j] + B[j];
}

__global__ void calc_len(const int* x, int* lengths) {
    __shared__ int cnt;
    if (threadIdx.x == 0) cnt = 0;
    __syncthreads();
    if (x[blockIdx.x * Tv + threadIdx.x] > 0) atomicAdd(&cnt, 1);
    __syncthreads();
    if (threadIdx.x == 0) lengths[blockIdx.x] = cnt;
}

// Zero the canary array at agent scope (visible to sc0sc1 spin loads).
__global__ void zero_canary(unsigned int* c) {
    __hip_atomic_store(c + (size_t)blockIdx.x * 256 + threadIdx.x, 0u,
                       __ATOMIC_RELAXED, __HIP_MEMORY_SCOPE_AGENT);
}

// X0 row = [embed[tok](300) | f(1) | zeros(19)] as bf16
__global__ void embed_pack(const int* __restrict__ x, const float* __restrict__ f,
                           const float* __restrict__ embed, unsigned short* __restrict__ X0) {
    int row = blockIdx.x;
    int tok = x[row];
    float fv = f[row];
    const float* e = embed + (size_t)tok * Ev;
    for (int k = threadIdx.x; k < K0PAD; k += 64) {
        float v = (k < Ev) ? e[k] : ((k == Ev) ? fv : 0.f);
        X0[(size_t)row * K0PAD + k] = f2bf(v);
    }
}

// ------- MFMA GEMM 64x64 per wave: C[M,N] = X[M,K] @ W[N,K]^T + bias[N] ----
__global__ __launch_bounds__(64) void mfma_gemm64(
    const unsigned short* __restrict__ X, int ldx,
    const unsigned short* __restrict__ Wt, int ldw, int wstride_z,
    const float* __restrict__ bias, int bstride_z,
    float* __restrict__ C, int ldc, size_t cstride_z, int K) {
    const int lane = threadIdx.x;
    const int z = blockIdx.z;
    const unsigned short* W = Wt + (size_t)z * wstride_z;
    const float* bz = bias + (size_t)z * bstride_z;
    float* Cz = C + (size_t)z * cstride_z;
    const int m0 = blockIdx.x * 64, n0 = blockIdx.y * 64;
    const int r = lane & 15, q = lane >> 4;
    const unsigned short* xp[4];
    const unsigned short* wp[4];
#pragma unroll
    for (int i = 0; i < 4; ++i) {
        xp[i] = X + (size_t)(m0 + 16 * i + r) * ldx + q * 8;
        wp[i] = W + (size_t)(n0 + 16 * i + r) * ldw + q * 8;
    }
    v4f acc[4][4];
#pragma unroll
    for (int i = 0; i < 4; ++i)
#pragma unroll
        for (int j = 0; j < 4; ++j) acc[i][j] = (v4f){0.f, 0.f, 0.f, 0.f};
#pragma unroll 2
    for (int k = 0; k < K; k += 32) {
        v8bf a[4], b[4];
#pragma unroll
        for (int i = 0; i < 4; ++i) { a[i] = *(const v8bf*)(xp[i] + k); b[i] = *(const v8bf*)(wp[i] + k); }
#pragma unroll
        for (int i = 0; i < 4; ++i)
#pragma unroll
            for (int j = 0; j < 4; ++j)
                acc[i][j] = __builtin_amdgcn_mfma_f32_16x16x32_bf16(a[i], b[j], acc[i][j], 0, 0, 0);
    }
#pragma unroll
    for (int j = 0; j < 4; ++j) {
        int col = n0 + 16 * j + r;
        float bv = bz[col];
#pragma unroll
        for (int i = 0; i < 4; ++i)
#pragma unroll
            for (int e = 0; e < 4; ++e)
                Cz[(size_t)(m0 + 16 * i + q * 4 + e) * ldc + col] = acc[i][j][e] + bv;
    }
}

// ---------------- autonomous-wave LSTM ----------------
// Hstate slot layout = MFMA A-fragment order (4096 dwords):
//   dword(r,c) = (r>=16 ? 2048 : 0) + ((c>>4)*64 + ((c>>2)&3)*16 + (r&15))*4 + (c&3)
// where r=batch, c=packed j-pair column (j = 2c, 2c+1).
// canary: [dir(2)][step(256)][wb(64)] dwords; 0 = pending, 1 = published.
__global__ __launch_bounds__(64) void lstm_wave(
    const float* __restrict__ Gin,
    const unsigned short* __restrict__ Wfrag,
    unsigned int* __restrict__ Hstate,
    unsigned int* __restrict__ canary,
    unsigned short* __restrict__ Hout,
    const int* __restrict__ lengths) {
    const int wb = blockIdx.x;           // 0..63: owns j = wb*4 .. wb*4+3
    const int d  = blockIdx.y;
    const int lane = threadIdx.x;        // 0..63
    const int q = lane >> 4;             // batch quad
    const int n = lane & 15;             // MFMA col = 4*jsub + gate
    const int jsub = n >> 2, p = n & 3;  // post-transpose: lane owns (jsub, b=q*4+p)
    const int j = wb * 4 + jsub;
    const int bA = q * 4 + p, bB = 16 + bA;

    // Whh B-fragments (gate-interleaved rows) -> registers
    v8bf wreg[8];
    {
        const unsigned short* wb0 = Wfrag + (size_t)d * WFRAG_Z
                                  + (size_t)wb * 4096 + lane * 8;
#pragma unroll
        for (int kt = 0; kt < 8; ++kt)
            wreg[kt] = *(const v8bf*)(wb0 + kt * 512);
    }
    const int ulenA = lengths[bA], ulenB = lengths[bB];
    float cA = 0.f, hA = 0.f, cB = 0.f, hB = 0.f;

    unsigned int* Hst = Hstate + (size_t)d * 256 * 4096;
    unsigned int* can_d = canary + (size_t)d * 256 * 64;
    const float* gin_d = Gin + (size_t)d * MROWS * GATES;

    // producer byte offsets within a slot (dword idx * 4 + half)
    const int c2 = j >> 1, hodd = (j & 1) * 2;
    const int pdw = ((c2 >> 4) * 64 + ((c2 >> 2) & 3) * 16 + (bA & 15)) * 4 + (c2 & 3);
    const int offA = pdw * 4 + hodd;               // batch low half
    const int offB = (2048 + pdw) * 4 + hodd;      // batch high half

    for (int s = 0; s < 256; ++s) {
        const int t = d ? 255 - s : s;
        const int slot = (s * 37) & 255;

        // Gin loads for this step (issued before the spin; drained by it)
        float ginA[4], ginB[4];
        {
            const float* ga = gin_d + ((size_t)bA * Tv + t) * GATES + j;
            const float* gb = gin_d + ((size_t)bB * Tv + t) * GATES + j;
#pragma unroll
            for (int e = 0; e < 4; ++e) { ginA[e] = ga[e * 256]; ginB[e] = gb[e * 256]; }
        }

        v4f T0 = {0.f, 0.f, 0.f, 0.f}, T1 = {0.f, 0.f, 0.f, 0.f};
        if (s > 0) {
            // ---- canary spin: 1 dword/lane covers all 64 producers of dir d
            {
                const unsigned int* cp = can_d + (size_t)(s - 1) * 64 + lane;
                int tries = 0;
                for (;;) {
                    unsigned int cv = ld_sys32(cp);
                    asm volatile("s_waitcnt vmcnt(0)" ::: "memory");
                    if (!__any(cv == 0u)) break;
                    if (++tries > (1 << 18)) break;       // safety valve
                }
                __builtin_amdgcn_sched_barrier(0);
            }
            // ---- plain cached fragment loads (fresh by protocol; L2-dedup)
            const int pslot = ((s - 1) * 37) & 255;
            const v4u* Hp4 = (const v4u*)(Hst + (size_t)pslot * 4096);
            AB af[16];
#pragma unroll
            for (int kt = 0; kt < 8; ++kt) {
                af[kt].u     = Hp4[kt * 64 + lane];
                af[8 + kt].u = Hp4[512 + kt * 64 + lane];
            }
            v4f acc0 = {0.f, 0.f, 0.f, 0.f}, acc1 = acc0;
#pragma unroll
            for (int kt = 0; kt < 8; ++kt) {
                acc0 = __builtin_amdgcn_mfma_f32_16x16x32_bf16(af[kt].v,     wreg[kt], acc0, 0, 0, 0);
                acc1 = __builtin_amdgcn_mfma_f32_16x16x32_bf16(af[8 + kt].v, wreg[kt], acc1, 0, 0, 0);
            }
            // 4x4 lane-quad transpose: (col=4jsub+gate, reg=batch) ->
            // lane p gets reg g = gate g for batch q*4+p. Masks 1,2 stay in quad.
            {
                float m0[4] = {acc0[0], acc0[1], acc0[2], acc0[3]};
                float m1[4] = {acc1[0], acc1[1], acc1[2], acc1[3]};
                float s0[4], s1[4], n0[4], n1[4];
#pragma unroll
                for (int e = 0; e < 4; ++e) { s0[e] = __shfl_xor(m0[e], 1); s1[e] = __shfl_xor(m1[e], 1); }
#pragma unroll
                for (int e = 0; e < 4; ++e) {
                    bool c1 = ((p ^ e) & 1);
                    n0[e] = c1 ? s0[e ^ 1] : m0[e];
                    n1[e] = c1 ? s1[e ^ 1] : m1[e];
                }
#pragma unroll
                for (int e = 0; e < 4; ++e) { s0[e] = __shfl_xor(n0[e], 2); s1[e] = __shfl_xor(n1[e], 2); }
#pragma unroll
                for (int e = 0; e < 4; ++e) {
                    bool c2_ = ((p ^ e) & 2);
                    T0[e] = c2_ ? s0[e ^ 2] : n0[e];
                    T1[e] = c2_ ? s1[e ^ 2] : n1[e];
                }
            }
        }
        // cell update for (j, bA) and (j, bB)
        unsigned short hAs, hBs;
        {
            bool mA = (t < ulenA), mB = (t < ulenB);
            {
                float ig = sigf(ginA[0] + T0[0]), fg = sigf(ginA[1] + T0[1]);
                float gg = tanhf2(ginA[2] + T0[2]), og = sigf(ginA[3] + T0[3]);
                float cn = fg * cA + ig * gg;
                float hn = og * tanhf2(cn);
                cA = mA ? cn : cA; hA = mA ? hn : hA;
            }
            {
                float ig = sigf(ginB[0] + T1[0]), fg = sigf(ginB[1] + T1[1]);
                float gg = tanhf2(ginB[2] + T1[2]), og = sigf(ginB[3] + T1[3]);
                float cn = fg * cB + ig * gg;
                float hn = og * tanhf2(cn);
                cB = mB ? cn : cB; hB = mB ? hn : hB;
            }
            hAs = f2bf(hA); hBs = f2bf(hB);
            char* bslot = (char*)(Hst + (size_t)slot * 4096);
            st_sys16(bslot + offA, hAs);
            st_sys16(bslot + offB, hBs);
            // release: data at IF before canary becomes visible
            asm volatile("s_waitcnt vmcnt(0)" ::: "memory");
            if (lane == 0)
                st_sys32(can_d + (size_t)s * 64 + wb, 1u);
        }
        // Hout off the critical path (consumed by next dispatch only)
        {
            Hout[((size_t)bA * Tv + t) * 512 + d * 256 + j] = (t < ulenA) ? hAs : (unsigned short)0;
            Hout[((size_t)bB * Tv + t) * 512 + d * 256 + j] = (t < ulenB) ? hBs : (unsigned short)0;
        }
    }
}

// ---------------- CRF ----------------
__global__ __launch_bounds__(64) void crf_kernel(
    const float* __restrict__ Y, const float* __restrict__ trans,
    const int* __restrict__ y0, const int* __restrict__ lengths,
    float* __restrict__ out) {
    int b = blockIdx.x, j = threadIdx.x;
    int len = lengths[b];
    float trj[64];
#pragma unroll
    for (int i = 0; i < 64; ++i) trj[i] = trans[j * 64 + i];
    __shared__ __align__(16) float s[64];
    s[j] = (j == 2) ? 0.f : -10000.f;
    __syncthreads();
    const float* yb = Y + (size_t)b * Tv * Kv;
    for (int t = 0; t < len; ++t) {
        float emit = yb[t * 64 + j];
        float m = -3.0e38f;
#pragma unroll
        for (int i = 0; i < 64; ++i) m = fmaxf(m, s[i] + trj[i]);
        float sum = 0.f;
#pragma unroll
        for (int i = 0; i < 64; ++i) sum += __expf(s[i] + trj[i] - m);
        float ns = m + __logf(sum) + emit;
        __syncthreads();
        s[j] = ns;
        __syncthreads();
    }
    float v = s[j];
    float M = v;
#pragma unroll
    for (int o = 32; o; o >>= 1) M = fmaxf(M, __shfl_xor(M, o));
    float e = __expf(v - M);
#pragma unroll
    for (int o = 32; o; o >>= 1) e += __shfl_xor(e, o);
    float Z = M + __logf(e);
    float gold = 0.f;
    for (int t = j; t < len; t += 64) {
        int yt = y0[b * Tv + t];
        int yp = (t == 0) ? 2 : y0[b * Tv + t - 1];
        gold += yb[t * 64 + yt] + trans[yt * 64 + yp];
    }
#pragma unroll
    for (int o = 32; o; o >>= 1) gold += __shfl_xor(gold, o);
    if (j == 0) out[b] = Z - gold;
}

// ---------------- host ----------------
extern "C" void kernel_launch(void* const* d_in, const int* in_sizes, int n_in,
                              void* d_out, int out_size, void* d_ws, size_t ws_size,
                              hipStream_t stream) {
    const int*   x     = (const int*)d_in[0];
    const float* f     = (const float*)d_in[1];
    const int*   y0    = (const int*)d_in[2];
    const float* embed = (const float*)d_in[3];
    const float* Wih0f = (const float*)d_in[4],  *Whh0f = (const float*)d_in[5];
    const float* bih0f = (const float*)d_in[6],  *bhh0f = (const float*)d_in[7];
    const float* Wih0b = (const float*)d_in[8],  *Whh0b = (const float*)d_in[9];
    const float* bih0b = (const float*)d_in[10], *bhh0b = (const float*)d_in[11];
    const float* Wih1f = (const float*)d_in[12], *Whh1f = (const float*)d_in[13];
    const float* bih1f = (const float*)d_in[14], *bhh1f = (const float*)d_in[15];
    const float* Wih1b = (const float*)d_in[16], *Whh1b = (const float*)d_in[17];
    const float* bih1b = (const float*)d_in[18], *bhh1b = (const float*)d_in[19];
    const float* out_w = (const float*)d_in[20];
    const float* out_b = (const float*)d_in[21];
    const float* trans = (const float*)d_in[22];

    char* ws = (char*)d_ws;
    size_t off = 0;
    auto alloc = [&](size_t bytes) -> void* {
        off = (off + 255) & ~(size_t)255;
        void* p = ws + off;
        off += bytes;
        return p;
    };
    unsigned short* X0   = (unsigned short*)alloc((size_t)MROWS * K0PAD * 2);
    unsigned short* dW0  = (unsigned short*)alloc((size_t)2 * 1024 * K0PAD * 2);
    unsigned short* dW1  = (unsigned short*)alloc((size_t)2 * 1024 * 512 * 2);
    unsigned short* dOW  = (unsigned short*)alloc((size_t)64 * 512 * 2);
    unsigned short* Wfrag= (unsigned short*)alloc((size_t)4 * WFRAG_Z * 2);
    float*          bias = (float*)alloc((size_t)4096 * 4);
    int*            lens = (int*)alloc((size_t)32 * 4);
    unsigned int*   can  = (unsigned int*)alloc((size_t)2 * 2 * 256 * 64 * 4);
    unsigned int*   Hst0 = (unsigned int*)alloc((size_t)2 * 256 * 4096 * 4);
    unsigned int*   Hst1 = (unsigned int*)alloc((size_t)2 * 256 * 4096 * 4);
    float*          Gin  = (float*)alloc((size_t)2 * MROWS * GATES * 4);
    unsigned short* H0   = (unsigned short*)alloc((size_t)MROWS * 512 * 2);
    unsigned short* H1   = (unsigned short*)alloc((size_t)MROWS * 512 * 2);
    float*          Y    = (float*)alloc((size_t)MROWS * Kv * 4);
    (void)ws_size; (void)in_sizes; (void)n_in; (void)out_size;

    // prep
    conv_weights<<<dim3(2048, 1, 5), 256, 0, stream>>>(Wih0f, Wih0b, Wih1f, Wih1b, out_w,
                                                       dW0, dW1, dOW);
    whh_frag<<<dim3(1024, 1, 4), 256, 0, stream>>>(Whh0f, Whh0b, Whh1f, Whh1b, Wfrag);
    bias_sum<<<16, 256, 0, stream>>>(bih0f, bhh0f, bih0b, bhh0b,
                                     bih1f, bhh1f, bih1b, bhh1b, bias);
    calc_len<<<32, 256, 0, stream>>>(x, lens);
    zero_canary<<<256, 256, 0, stream>>>(can);        // 2 layers x 2 dirs x 256 x 64
    embed_pack<<<MROWS, 64, 0, stream>>>(x, f, embed, X0);

    // layer 0 (both dirs in one launch)
    mfma_gemm64<<<dim3(MROWS / 64, 16, 2), 64, 0, stream>>>(
        X0, K0PAD, dW0, K0PAD, 1024 * K0PAD, bias, 1024,
        Gin, GATES, (size_t)MROWS * GATES, K0PAD);
    lstm_wave<<<dim3(64, 2), 64, 0, stream>>>(Gin, Wfrag, Hst0, can, H0, lens);

    // layer 1
    mfma_gemm64<<<dim3(MROWS / 64, 16, 2), 64, 0, stream>>>(
        H0, 512, dW1, 512, 1024 * 512, bias + 2048, 1024,
        Gin, GATES, (size_t)MROWS * GATES, 512);
    lstm_wave<<<dim3(64, 2), 64, 0, stream>>>(Gin, Wfrag + (size_t)2 * WFRAG_Z,
                                              Hst1, can + (size_t)2 * 256 * 64, H1, lens);

    // emissions + CRF
    mfma_gemm64<<<dim3(MROWS / 64, 1, 1), 64, 0, stream>>>(
        H1, 512, dOW, 512, 0, out_b, 0, Y, Kv, 0, 512);
    crf_kernel<<<32, 64, 0, stream>>>(Y, trans, y0, lens, (float*)d_out);
}

// Round 4
// 1779.911 us; speedup vs baseline: 1.3442x; 1.3442x over previous
//
#include <hip/hip_runtime.h>
#include <hip/hip_bf16.h>

// ---------------------------------------------------------------------------
// LSTM-CRF forward on MI355X.
// R12 = R10 fused NaN-sentinel protocol (best measured: 570us) + two traffic
// fixes diagnosed from R10/R11 counters:
//   1. Gin gate-innermost layout via WEIGHT-ROW PERMUTATION at prep
//      (n' = j*4+gate). R10's 314MB FETCH was ~256MB Gin line-amplification
//      (4 waves on 4 XCDs splitting every 64B line). Now each wave reads 32
//      consecutive floats per (b,t) -> 1x amplification, float4 loads.
//      GEMM untouched (still coalesced); zero runtime cost.
//   2. 8 j's per wave -> 32 waves/dir (64 blocks): halves the redundant
//      sc-bypass spin traffic (2MB -> 1MB/step). Retry loop checks only
//      colset0 (NaN in A poisons ALL cols); colset1 MFMAs run once after.
// R11 post-mortem: canary+cached un-fused the exchange into 3 serial IF
// round-trips (570->1030us) and FETCH didn't drop -> reverted to fused spin.
// ---------------------------------------------------------------------------

#define Bv 32
#define Tv 256
#define Ev 300
#define HDv 256
#define Kv 64
#define MROWS (Bv * Tv)          // 8192
#define K0PAD 320                // 301 padded to mult of 32
#define GATES 1024               // 4*HD
#define WFRAG_Z 262144           // shorts per (layer,dir) weight block
#define SENT 0x7FC07FC0u         // bf16 NaN | NaN: poisons MFMA accs

typedef __bf16 v8bf __attribute__((ext_vector_type(8)));
typedef float  v4f  __attribute__((ext_vector_type(4)));
typedef unsigned int v4u __attribute__((ext_vector_type(4)));

union AB { v4u u; v8bf v; };

__device__ __forceinline__ unsigned short f2bf(float f) {
    unsigned u = __float_as_uint(f);
    unsigned r = (u + 0x7fffu + ((u >> 16) & 1u)) >> 16;
    return (unsigned short)r;
}
__device__ __forceinline__ float sigf(float x) { return 1.0f / (1.0f + __expf(-x)); }
__device__ __forceinline__ float tanhf2(float x) {
    x = fminf(15.f, fmaxf(-15.f, x));
    float e = __expf(2.f * x);
    return (e - 1.f) / (e + 1.f);
}
// IF-coherent 16B load: bypasses L1/L2 so retries observe producer stores.
__device__ __forceinline__ v4u ld_sys(const v4u* p) {
    v4u r;
    asm volatile("global_load_dwordx4 %0, %1, off sc0 sc1"
                 : "=v"(r) : "v"(p) : "memory");
    return r;
}
// IF-coherent 16-bit publish store.
__device__ __forceinline__ void st_sys16(void* p, unsigned short v) {
    unsigned int vv = v;
    asm volatile("global_store_short %0, %1, off sc0 sc1"
                 :: "v"(p), "v"(vv) : "memory");
}

// ---------------- prep kernels ----------------

// For dW0/dW1 (z<4): physical row n' = j*4 + gate  (source row gate*256+j).
// Gin (GEMM output) then has gates innermost -> lstm reads contiguous float4s.
__global__ void conv_weights(const float* w0f, const float* w0b,
                             const float* w1f, const float* w1b,
                             const float* outw,
                             unsigned short* dW0, unsigned short* dW1,
                             unsigned short* dOW) {
    int z = blockIdx.z;
    const float* src; unsigned short* dst; int rows, kin, kout;
    if (z == 0)      { src = w0f;  dst = dW0;                rows = 1024; kin = 301; kout = K0PAD; }
    else if (z == 1) { src = w0b;  dst = dW0 + 1024 * K0PAD; rows = 1024; kin = 301; kout = K0PAD; }
    else if (z == 2) { src = w1f;  dst = dW1;                rows = 1024; kin = 512; kout = 512; }
    else if (z == 3) { src = w1b;  dst = dW1 + 1024 * 512;   rows = 1024; kin = 512; kout = 512; }
    else             { src = outw; dst = dOW;                rows = 64;   kin = 512; kout = 512; }
    int idx = blockIdx.x * 256 + threadIdx.x;
    if (idx >= rows * kout) return;
    int j = idx / kout, k = idx - j * kout;
    int srow = (z < 4) ? ((j & 3) * 256 + (j >> 2)) : j;
    dst[idx] = (k < kin) ? f2bf(src[srow * kin + k]) : (unsigned short)0;
}

// Whh [1024,256] fp32 -> bf16 MFMA B-fragment order, gate-interleaved:
// per (layer*2+dir) z: [wb(32)][cs(2)][kt(8)][lane(64)][e(8)]
// B-col n = lane&15 = 4*jsub' + gate; source row = gate*256 + wb*8 + cs*4 + jsub',
// k = kt*32 + (lane>>4)*8 + e.  One wave (2 colsets) = all 4 gates x 8 j's.
__global__ void whh_frag(const float* h0f, const float* h0b,
                         const float* h1f, const float* h1b, unsigned short* Wfrag) {
    int z = blockIdx.z;
    const float* src = (z == 0) ? h0f : (z == 1) ? h0b : (z == 2) ? h1f : h1b;
    unsigned short* dst = Wfrag + (size_t)z * WFRAG_Z;
    int idx = blockIdx.x * 256 + threadIdx.x;          // 0..262143
    int e = idx & 7, ln = (idx >> 3) & 63, kt = (idx >> 9) & 7;
    int cs = (idx >> 12) & 1, wb = idx >> 13;
    int n = ln & 15;
    int jsub = n >> 2, gate = n & 3;
    int row = gate * 256 + wb * 8 + cs * 4 + jsub;
    int k = kt * 32 + (ln >> 4) * 8 + e;
    dst[idx] = f2bf(src[row * 256 + k]);
}

// bias in permuted (gate-innermost) order to match Gin cols.
__global__ void bias_sum(const float* a0, const float* b0, const float* a1, const float* b1,
                         const float* a2, const float* b2, const float* a3, const float* b3,
                         float* bias) {
    int idx = blockIdx.x * 256 + threadIdx.x;      // 0..4095
    int dl = idx >> 10, j = idx & 1023;
    const float* A = (dl == 0) ? a0 : (dl == 1) ? a1 : (dl == 2) ? a2 : a3;
    const float* B = (dl == 0) ? b0 : (dl == 1) ? b1 : (dl == 2) ? b2 : b3;
    int srow = (j & 3) * 256 + (j >> 2);
    bias[idx] = A[srow] + B[srow];
}

__global__ void calc_len(const int* x, int* lengths) {
    __shared__ int cnt;
    if (threadIdx.x == 0) cnt = 0;
    __syncthreads();
    if (x[blockIdx.x * Tv + threadIdx.x] > 0) atomicAdd(&cnt, 1);
    __syncthreads();
    if (threadIdx.x == 0) lengths[blockIdx.x] = cnt;
}

// Sentinel-init both Hstate buffers at IF scope.
__global__ void init_sent(unsigned int* h0, unsigned int* h1) {
    unsigned int* p = (blockIdx.y ? h1 : h0) + (size_t)blockIdx.x * 1024 + threadIdx.x;
#pragma unroll
    for (int k = 0; k < 4; ++k)
        __hip_atomic_store(p + k * 256, SENT, __ATOMIC_RELAXED, __HIP_MEMORY_SCOPE_AGENT);
}

// X0 row = [embed[tok](300) | f(1) | zeros(19)] as bf16
__global__ void embed_pack(const int* __restrict__ x, const float* __restrict__ f,
                           const float* __restrict__ embed, unsigned short* __restrict__ X0) {
    int row = blockIdx.x;
    int tok = x[row];
    float fv = f[row];
    const float* e = embed + (size_t)tok * Ev;
    for (int k = threadIdx.x; k < K0PAD; k += 64) {
        float v = (k < Ev) ? e[k] : ((k == Ev) ? fv : 0.f);
        X0[(size_t)row * K0PAD + k] = f2bf(v);
    }
}

// ------- MFMA GEMM 64x64 per wave: C[M,N] = X[M,K] @ W[N,K]^T + bias[N] ----
__global__ __launch_bounds__(64) void mfma_gemm64(
    const unsigned short* __restrict__ X, int ldx,
    const unsigned short* __restrict__ Wt, int ldw, int wstride_z,
    const float* __restrict__ bias, int bstride_z,
    float* __restrict__ C, int ldc, size_t cstride_z, int K) {
    const int lane = threadIdx.x;
    const int z = blockIdx.z;
    const unsigned short* W = Wt + (size_t)z * wstride_z;
    const float* bz = bias + (size_t)z * bstride_z;
    float* Cz = C + (size_t)z * cstride_z;
    const int m0 = blockIdx.x * 64, n0 = blockIdx.y * 64;
    const int r = lane & 15, q = lane >> 4;
    const unsigned short* xp[4];
    const unsigned short* wp[4];
#pragma unroll
    for (int i = 0; i < 4; ++i) {
        xp[i] = X + (size_t)(m0 + 16 * i + r) * ldx + q * 8;
        wp[i] = W + (size_t)(n0 + 16 * i + r) * ldw + q * 8;
    }
    v4f acc[4][4];
#pragma unroll
    for (int i = 0; i < 4; ++i)
#pragma unroll
        for (int j = 0; j < 4; ++j) acc[i][j] = (v4f){0.f, 0.f, 0.f, 0.f};
#pragma unroll 2
    for (int k = 0; k < K; k += 32) {
        v8bf a[4], b[4];
#pragma unroll
        for (int i = 0; i < 4; ++i) { a[i] = *(const v8bf*)(xp[i] + k); b[i] = *(const v8bf*)(wp[i] + k); }
#pragma unroll
        for (int i = 0; i < 4; ++i)
#pragma unroll
            for (int j = 0; j < 4; ++j)
                acc[i][j] = __builtin_amdgcn_mfma_f32_16x16x32_bf16(a[i], b[j], acc[i][j], 0, 0, 0);
    }
#pragma unroll
    for (int j = 0; j < 4; ++j) {
        int col = n0 + 16 * j + r;
        float bv = bz[col];
#pragma unroll
        for (int i = 0; i < 4; ++i)
#pragma unroll
            for (int e = 0; e < 4; ++e)
                Cz[(size_t)(m0 + 16 * i + q * 4 + e) * ldc + col] = acc[i][j][e] + bv;
    }
}

// ---------------- autonomous-wave LSTM (fused NaN-sentinel spin) -----------
// Hstate slot layout = MFMA A-fragment order (4096 dwords):
//   dword(r,c) = (r>=16 ? 2048 : 0) + ((c>>4)*64 + ((c>>2)&3)*16 + (r&15))*4 + (c&3)
// where r=batch, c=packed j-pair column (j = 2c, 2c+1).
__global__ __launch_bounds__(64) void lstm_wave(
    const float* __restrict__ Gin,
    const unsigned short* __restrict__ Wfrag,
    unsigned int* __restrict__ Hstate,
    unsigned short* __restrict__ Hout,
    const int* __restrict__ lengths) {
    const int wb = blockIdx.x;           // 0..31: owns j = wb*8 .. wb*8+7
    const int d  = blockIdx.y;
    const int lane = threadIdx.x;        // 0..63
    const int q = lane >> 4;             // batch quad
    const int n = lane & 15;             // MFMA col = 4*jsub' + gate
    const int js = n >> 2, p = n & 3;    // post-transpose lane role
    const int jA = wb * 8 + js;          // colset0 j
    const int jB = jA + 4;               // colset1 j
    const int bA = q * 4 + p, bB = 16 + bA;

    // Whh B-fragments -> registers: wreg[cs][kt]
    v8bf wreg[2][8];
    {
        const unsigned short* wb0 = Wfrag + (size_t)d * WFRAG_Z
                                  + (size_t)wb * 8192 + lane * 8;
#pragma unroll
        for (int cs = 0; cs < 2; ++cs)
#pragma unroll
            for (int kt = 0; kt < 8; ++kt)
                wreg[cs][kt] = *(const v8bf*)(wb0 + cs * 4096 + kt * 512);
    }
    const int ulenA = lengths[bA], ulenB = lengths[bB];
    float cA0 = 0.f, hA0 = 0.f, cA1 = 0.f, hA1 = 0.f;
    float cB0 = 0.f, hB0 = 0.f, cB1 = 0.f, hB1 = 0.f;

    unsigned int* Hst = Hstate + (size_t)d * 256 * 4096;
    const float* gin_d = Gin + (size_t)d * MROWS * GATES;

    // producer byte offsets within a slot (batches 0-15; +8192 for 16-31)
    auto mkoff = [&](int j) -> int {
        int c2 = j >> 1, hodd = (j & 1) * 2;
        int pdw = ((c2 >> 4) * 64 + ((c2 >> 2) & 3) * 16 + (bA & 15)) * 4 + (c2 & 3);
        return pdw * 4 + hodd;
    };
    const int offA = mkoff(jA), offBn = mkoff(jB);

    // 4x4 lane-quad transpose: (col=4jsub'+gate, reg=batch) ->
    // lane p gets reg g = gate g for batch q*4+p. Masks 1,2 stay in quad.
    auto quadT = [&](v4f a0, v4f a1, float* T0, float* T1) {
        float m0[4] = {a0[0], a0[1], a0[2], a0[3]};
        float m1[4] = {a1[0], a1[1], a1[2], a1[3]};
        float s0[4], s1[4], n0[4], n1[4];
#pragma unroll
        for (int e = 0; e < 4; ++e) { s0[e] = __shfl_xor(m0[e], 1); s1[e] = __shfl_xor(m1[e], 1); }
#pragma unroll
        for (int e = 0; e < 4; ++e) {
            bool c1 = ((p ^ e) & 1);
            n0[e] = c1 ? s0[e ^ 1] : m0[e];
            n1[e] = c1 ? s1[e ^ 1] : m1[e];
        }
#pragma unroll
        for (int e = 0; e < 4; ++e) { s0[e] = __shfl_xor(n0[e], 2); s1[e] = __shfl_xor(n1[e], 2); }
#pragma unroll
        for (int e = 0; e < 4; ++e) {
            bool cc = ((p ^ e) & 2);
            T0[e] = cc ? s0[e ^ 2] : n0[e];
            T1[e] = cc ? s1[e ^ 2] : n1[e];
        }
    };
    auto cell = [&](float4 g, const float* T, float& c, float& h, bool mk) {
        float ig = sigf(g.x + T[0]), fg = sigf(g.y + T[1]);
        float gg = tanhf2(g.z + T[2]), og = sigf(g.w + T[3]);
        float cn = fg * c + ig * gg;
        float hn = og * tanhf2(cn);
        c = mk ? cn : c; h = mk ? hn : h;
    };

    for (int s = 0; s < 256; ++s) {
        const int t = d ? 255 - s : s;
        const int slot = (s * 37) & 255;

        // Gin: gate-innermost layout -> 4 contiguous float4 loads, no waste
        float4 gA0, gA1, gB0, gB1;
        {
            const float* ga = gin_d + ((size_t)bA * Tv + t) * GATES + wb * 32 + js * 4;
            const float* gb = gin_d + ((size_t)bB * Tv + t) * GATES + wb * 32 + js * 4;
            gA0 = *(const float4*)ga;  gA1 = *(const float4*)(ga + 16);
            gB0 = *(const float4*)gb;  gB1 = *(const float4*)(gb + 16);
        }

        float TA0[4] = {0.f, 0.f, 0.f, 0.f}, TB0[4] = {0.f, 0.f, 0.f, 0.f};
        float TA1[4] = {0.f, 0.f, 0.f, 0.f}, TB1[4] = {0.f, 0.f, 0.f, 0.f};
        if (s > 0) {
            const int pslot = ((s - 1) * 37) & 255;
            const v4u* Hp4 = (const v4u*)(Hst + (size_t)pslot * 4096);
            AB af[16];
#pragma unroll
            for (int kt = 0; kt < 8; ++kt) {
                af[kt].u     = ld_sys(Hp4 + kt * 64 + lane);
                af[8 + kt].u = ld_sys(Hp4 + 512 + kt * 64 + lane);
            }
            v4f acc0, acc1;
            int tries = 0;
            for (;;) {
                asm volatile("s_waitcnt vmcnt(0)" ::: "memory");
                __builtin_amdgcn_sched_barrier(0);
                acc0 = (v4f){0.f, 0.f, 0.f, 0.f};
                acc1 = acc0;
#pragma unroll
                for (int kt = 0; kt < 8; ++kt) {
                    acc0 = __builtin_amdgcn_mfma_f32_16x16x32_bf16(af[kt].v,     wreg[0][kt], acc0, 0, 0, 0);
                    acc1 = __builtin_amdgcn_mfma_f32_16x16x32_bf16(af[8 + kt].v, wreg[0][kt], acc1, 0, 0, 0);
                }
                // NaN in A poisons every column -> colset0 check covers all.
                int bad = 0;
#pragma unroll
                for (int e = 0; e < 4; ++e) {
                    bad |= ((__float_as_uint(acc0[e]) & 0x7f800000u) == 0x7f800000u);
                    bad |= ((__float_as_uint(acc1[e]) & 0x7f800000u) == 0x7f800000u);
                }
                if (!__any(bad)) break;
                if (++tries > (1 << 16)) break;        // safety valve
#pragma unroll
                for (int kt = 0; kt < 8; ++kt) {
                    af[kt].u     = ld_sys(Hp4 + kt * 64 + lane);
                    af[8 + kt].u = ld_sys(Hp4 + 512 + kt * 64 + lane);
                }
            }
            // colset1 once, after data is known-clean
            v4f acc2 = (v4f){0.f, 0.f, 0.f, 0.f}, acc3 = acc2;
#pragma unroll
            for (int kt = 0; kt < 8; ++kt) {
                acc2 = __builtin_amdgcn_mfma_f32_16x16x32_bf16(af[kt].v,     wreg[1][kt], acc2, 0, 0, 0);
                acc3 = __builtin_amdgcn_mfma_f32_16x16x32_bf16(af[8 + kt].v, wreg[1][kt], acc3, 0, 0, 0);
            }
            quadT(acc0, acc1, TA0, TB0);
            quadT(acc2, acc3, TA1, TB1);
        }
        // cell updates: (jA,bA) (jB,bA) (jA,bB) (jB,bB)
        bool mA = (t < ulenA), mB = (t < ulenB);
        cell(gA0, TA0, cA0, hA0, mA);
        cell(gA1, TA1, cA1, hA1, mA);
        cell(gB0, TB0, cB0, hB0, mB);
        cell(gB1, TB1, cB1, hB1, mB);
        unsigned short h0s = f2bf(hA0), h1s = f2bf(hA1);
        unsigned short h2s = f2bf(hB0), h3s = f2bf(hB1);
        {
            char* bslot = (char*)(Hst + (size_t)slot * 4096);
            st_sys16(bslot + offA, h0s);
            st_sys16(bslot + offBn, h1s);
            st_sys16(bslot + 8192 + offA, h2s);
            st_sys16(bslot + 8192 + offBn, h3s);
        }
        // Hout off the critical path (consumed by next dispatch only)
        {
            size_t rA = ((size_t)bA * Tv + t) * 512 + d * 256;
            size_t rB = ((size_t)bB * Tv + t) * 512 + d * 256;
            Hout[rA + jA] = mA ? h0s : (unsigned short)0;
            Hout[rA + jB] = mA ? h1s : (unsigned short)0;
            Hout[rB + jA] = mB ? h2s : (unsigned short)0;
            Hout[rB + jB] = mB ? h3s : (unsigned short)0;
        }
    }
}

// ---------------- CRF ----------------
__global__ __launch_bounds__(64) void crf_kernel(
    const float* __restrict__ Y, const float* __restrict__ trans,
    const int* __restrict__ y0, const int* __restrict__ lengths,
    float* __restrict__ out) {
    int b = blockIdx.x, j = threadIdx.x;
    int len = lengths[b];
    float trj[64];
#pragma unroll
    for (int i = 0; i < 64; ++i) trj[i] = trans[j * 64 + i];
    __shared__ __align__(16) float s[64];
    s[j] = (j == 2) ? 0.f : -10000.f;
    __syncthreads();
    const float* yb = Y + (size_t)b * Tv * Kv;
    for (int t = 0; t < len; ++t) {
        float emit = yb[t * 64 + j];
        float m = -3.0e38f;
#pragma unroll
        for (int i = 0; i < 64; ++i) m = fmaxf(m, s[i] + trj[i]);
        float sum = 0.f;
#pragma unroll
        for (int i = 0; i < 64; ++i) sum += __expf(s[i] + trj[i] - m);
        float ns = m + __logf(sum) + emit;
        __syncthreads();
        s[j] = ns;
        __syncthreads();
    }
    float v = s[j];
    float M = v;
#pragma unroll
    for (int o = 32; o; o >>= 1) M = fmaxf(M, __shfl_xor(M, o));
    float e = __expf(v - M);
#pragma unroll
    for (int o = 32; o; o >>= 1) e += __shfl_xor(e, o);
    float Z = M + __logf(e);
    float gold = 0.f;
    for (int t = j; t < len; t += 64) {
        int yt = y0[b * Tv + t];
        int yp = (t == 0) ? 2 : y0[b * Tv + t - 1];
        gold += yb[t * 64 + yt] + trans[yt * 64 + yp];
    }
#pragma unroll
    for (int o = 32; o; o >>= 1) gold += __shfl_xor(gold, o);
    if (j == 0) out[b] = Z - gold;
}

// ---------------- host ----------------
extern "C" void kernel_launch(void* const* d_in, const int* in_sizes, int n_in,
                              void* d_out, int out_size, void* d_ws, size_t ws_size,
                              hipStream_t stream) {
    const int*   x     = (const int*)d_in[0];
    const float* f     = (const float*)d_in[1];
    const int*   y0    = (const int*)d_in[2];
    const float* embed = (const float*)d_in[3];
    const float* Wih0f = (const float*)d_in[4],  *Whh0f = (const float*)d_in[5];
    const float* bih0f = (const float*)d_in[6],  *bhh0f = (const float*)d_in[7];
    const float* Wih0b = (const float*)d_in[8],  *Whh0b = (const float*)d_in[9];
    const float* bih0b = (const float*)d_in[10], *bhh0b = (const float*)d_in[11];
    const float* Wih1f = (const float*)d_in[12], *Whh1f = (const float*)d_in[13];
    const float* bih1f = (const float*)d_in[14], *bhh1f = (const float*)d_in[15];
    const float* Wih1b = (const float*)d_in[16], *Whh1b = (const float*)d_in[17];
    const float* bih1b = (const float*)d_in[18], *bhh1b = (const float*)d_in[19];
    const float* out_w = (const float*)d_in[20];
    const float* out_b = (const float*)d_in[21];
    const float* trans = (const float*)d_in[22];

    char* ws = (char*)d_ws;
    size_t off = 0;
    auto alloc = [&](size_t bytes) -> void* {
        off = (off + 255) & ~(size_t)255;
        void* p = ws + off;
        off += bytes;
        return p;
    };
    unsigned short* X0   = (unsigned short*)alloc((size_t)MROWS * K0PAD * 2);
    unsigned short* dW0  = (unsigned short*)alloc((size_t)2 * 1024 * K0PAD * 2);
    unsigned short* dW1  = (unsigned short*)alloc((size_t)2 * 1024 * 512 * 2);
    unsigned short* dOW  = (unsigned short*)alloc((size_t)64 * 512 * 2);
    unsigned short* Wfrag= (unsigned short*)alloc((size_t)4 * WFRAG_Z * 2);
    float*          bias = (float*)alloc((size_t)4096 * 4);
    int*            lens = (int*)alloc((size_t)32 * 4);
    unsigned int*   Hst0 = (unsigned int*)alloc((size_t)2 * 256 * 4096 * 4);
    unsigned int*   Hst1 = (unsigned int*)alloc((size_t)2 * 256 * 4096 * 4);
    float*          Gin  = (float*)alloc((size_t)2 * MROWS * GATES * 4);
    unsigned short* H0   = (unsigned short*)alloc((size_t)MROWS * 512 * 2);
    unsigned short* H1   = (unsigned short*)alloc((size_t)MROWS * 512 * 2);
    float*          Y    = (float*)alloc((size_t)MROWS * Kv * 4);
    (void)ws_size; (void)in_sizes; (void)n_in; (void)out_size;

    // prep
    conv_weights<<<dim3(2048, 1, 5), 256, 0, stream>>>(Wih0f, Wih0b, Wih1f, Wih1b, out_w,
                                                       dW0, dW1, dOW);
    whh_frag<<<dim3(1024, 1, 4), 256, 0, stream>>>(Whh0f, Whh0b, Whh1f, Whh1b, Wfrag);
    bias_sum<<<16, 256, 0, stream>>>(bih0f, bhh0f, bih0b, bhh0b,
                                     bih1f, bhh1f, bih1b, bhh1b, bias);
    calc_len<<<32, 256, 0, stream>>>(x, lens);
    init_sent<<<dim3(2048, 2), 256, 0, stream>>>(Hst0, Hst1);
    embed_pack<<<MROWS, 64, 0, stream>>>(x, f, embed, X0);

    // layer 0 (both dirs in one launch)
    mfma_gemm64<<<dim3(MROWS / 64, 16, 2), 64, 0, stream>>>(
        X0, K0PAD, dW0, K0PAD, 1024 * K0PAD, bias, 1024,
        Gin, GATES, (size_t)MROWS * GATES, K0PAD);
    lstm_wave<<<dim3(32, 2), 64, 0, stream>>>(Gin, Wfrag, Hst0, H0, lens);

    // layer 1
    mfma_gemm64<<<dim3(MROWS / 64, 16, 2), 64, 0, stream>>>(
        H0, 512, dW1, 512, 1024 * 512, bias + 2048, 1024,
        Gin, GATES, (size_t)MROWS * GATES, 512);
    lstm_wave<<<dim3(32, 2), 64, 0, stream>>>(Gin, Wfrag + (size_t)2 * WFRAG_Z,
                                              Hst1, H1, lens);

    // emissions + CRF
    mfma_gemm64<<<dim3(MROWS / 64, 1, 1), 64, 0, stream>>>(
        H1, 512, dOW, 512, 0, out_b, 0, Y, Kv, 0, 512);
    crf_kernel<<<32, 64, 0, stream>>>(Y, trans, y0, lens, (float*)d_out);
}